// Round 1
// baseline (453.908 us; speedup 1.0000x reference)
//
#include <hip/hip_runtime.h>

#define B 8
#define N 2048
#define KF 256
#define DF 64
#define LOG2E 1.44269504088896340736f

// ---- helpers ----
__device__ __forceinline__ unsigned fenc(float f) {
    unsigned b = __float_as_uint(f);
    return b ^ ((unsigned)((int)b >> 31) | 0x80000000u);
}
__device__ __forceinline__ float fdec(unsigned k) {
    unsigned b = (k & 0x80000000u) ? (k ^ 0x80000000u) : ~k;
    return __uint_as_float(b);
}
__device__ __forceinline__ float lrelu(float x) { return fmaxf(x, 0.2f * x); }
__device__ __forceinline__ float eluf(float x) { return x > 0.f ? x : expm1f(x); }

// ---- zero-init scratch (denom + f1max) ----
__global__ void k_zero(float* __restrict__ denom, unsigned* __restrict__ fmax) {
    int i = blockIdx.x * 256 + threadIdx.x;
    if (i < B * N) denom[i] = 0.f;
    if (i < B) fmax[i] = 0u;
}

// ---- A: Wh = h @ W  (16 rows per block, W staged in LDS in 2 k-chunks) ----
__global__ __launch_bounds__(256) void k_wh(const float* __restrict__ h,
                                            const float* __restrict__ W,
                                            float* __restrict__ Wh) {
    __shared__ float lh[16 * KF];       // 16 KB
    __shared__ float lw[128 * DF];      // 32 KB
    int t = threadIdx.x;
    long rowbase = (long)blockIdx.x * 16;

    // load 16 h rows (contiguous) as float4
    const float4* h4 = (const float4*)(h + rowbase * KF);
    float4* lh4 = (float4*)lh;
    for (int idx = t; idx < 16 * KF / 4; idx += 256) lh4[idx] = h4[idx];

    int lane = t & 63, wv = t >> 6;
    int r0 = wv * 4;
    float acc[4] = {0.f, 0.f, 0.f, 0.f};

    for (int kc = 0; kc < 2; kc++) {
        __syncthreads();
        const float4* W4 = (const float4*)(W + kc * 128 * DF);
        float4* lw4 = (float4*)lw;
        for (int idx = t; idx < 128 * DF / 4; idx += 256) lw4[idx] = W4[idx];
        __syncthreads();
        for (int k = 0; k < 128; k++) {
            float wk = lw[k * DF + lane];   // 2-way bank alias: free
            #pragma unroll
            for (int r = 0; r < 4; r++)
                acc[r] += lh[(r0 + r) * KF + kc * 128 + k] * wk;  // broadcast
        }
    }
    #pragma unroll
    for (int r = 0; r < 4; r++)
        Wh[(rowbase + r0 + r) * DF + lane] = acc[r];
}

// ---- B: f1 = Wh@a1, f2 = Wh@a2, per-batch max of f1 (one wave per row) ----
__global__ __launch_bounds__(256) void k_f12(const float* __restrict__ Wh,
                                             const float* __restrict__ a,
                                             float* __restrict__ f1,
                                             float* __restrict__ f2,
                                             unsigned* __restrict__ f1maxU) {
    int t = threadIdx.x;
    int lane = t & 63, wv = t >> 6;
    long row = (long)blockIdx.x * 4 + wv;
    float x = Wh[row * DF + lane];
    float s1 = x * a[lane];
    float s2 = x * a[DF + lane];
    #pragma unroll
    for (int off = 32; off; off >>= 1) {
        s1 += __shfl_xor(s1, off, 64);
        s2 += __shfl_xor(s2, off, 64);
    }
    if (lane == 0) {
        f1[row] = s1;
        f2[row] = s2;
        atomicMax(f1maxU + (row >> 11), fenc(s1));
    }
}

// ---- D: denom[b,j] = sum_i exp(leaky(f1_i+f2_j) - m_j), chunked over i ----
#define IC 8
#define ICH (N / IC)   // 256
__global__ __launch_bounds__(256) void k_denom(const float* __restrict__ f1,
                                               const float* __restrict__ f2,
                                               const unsigned* __restrict__ f1maxU,
                                               float* __restrict__ denom) {
    __shared__ float lf1[ICH];
    int t = threadIdx.x;
    int b = blockIdx.z;
    int j = blockIdx.x * 256 + t;
    int i0 = blockIdx.y * ICH;
    lf1[t] = f1[b * N + i0 + t];
    __syncthreads();
    float F1m = fdec(f1maxU[b]);
    float f2j = f2[b * N + j];
    float m = lrelu(F1m + f2j);
    float s = 0.f;
    for (int ii = 0; ii < ICH; ii++) {
        float l = lrelu(lf1[ii] + f2j);
        s += exp2f((l - m) * LOG2E);
    }
    atomicAdd(&denom[b * N + j], s);
}

// ---- pack per-j constants: {f2, m, 1/denom, 0} ----
__global__ void k_pack(const float* __restrict__ f2,
                       const float* __restrict__ denom,
                       const unsigned* __restrict__ f1maxU,
                       float4* __restrict__ col) {
    int idx = blockIdx.x * 256 + threadIdx.x;   // 16384
    int b = idx >> 11;
    float F1m = fdec(f1maxU[b]);
    float f2j = f2[idx];
    float m = lrelu(F1m + f2j);
    col[idx] = make_float4(f2j, m, 1.0f / denom[idx], 0.f);
}

// ---- E: main contraction. One thread per output row i; j chunked by NC. ----
template <int NC, bool DIRECT>
__global__ __launch_bounds__(256) void k_main(const float* __restrict__ Wh,
                                              const float* __restrict__ f1,
                                              const float4* __restrict__ col,
                                              float* __restrict__ outp) {
    int t = threadIdx.x;
    int c = blockIdx.x, iblk = blockIdx.y, b = blockIdx.z;
    long row = (long)b * N + iblk * 256 + t;
    float f1i = f1[row];
    float4 acc[16];
    #pragma unroll
    for (int q = 0; q < 16; q++) acc[q] = make_float4(0.f, 0.f, 0.f, 0.f);

    const int CH = N / NC;
    long jbase = (long)b * N + (long)c * CH;
    const float4* wh4 = (const float4*)Wh + jbase * 16;

    for (int jj = 0; jj < CH; jj++) {
        float4 cv = col[jbase + jj];                 // wave-uniform -> s_load
        float l = lrelu(f1i + cv.x);
        float w = exp2f((l - cv.y) * LOG2E) * cv.z;
        const float4* wr = wh4 + (long)jj * 16;      // wave-uniform -> s_load
        #pragma unroll
        for (int q = 0; q < 16; q++) {
            float4 v = wr[q];
            acc[q].x += w * v.x;
            acc[q].y += w * v.y;
            acc[q].z += w * v.z;
            acc[q].w += w * v.w;
        }
    }

    if (DIRECT) {
        float4* o4 = (float4*)outp + row * 16;
        #pragma unroll
        for (int q = 0; q < 16; q++) {
            float4 v = acc[q];
            v.x = eluf(v.x); v.y = eluf(v.y); v.z = eluf(v.z); v.w = eluf(v.w);
            o4[q] = v;
        }
    } else {
        float4* p4 = (float4*)outp + ((long)c * (B * N) + row) * 16;
        #pragma unroll
        for (int q = 0; q < 16; q++) p4[q] = acc[q];
    }
}

// ---- F: reduce NC partials + ELU ----
template <int NC>
__global__ void k_reduce(const float4* __restrict__ part, float4* __restrict__ out) {
    long idx = (long)blockIdx.x * 256 + threadIdx.x;   // 262144 float4s
    const long stride = (long)B * N * 16;
    float4 s = part[idx];
    #pragma unroll
    for (int c = 1; c < NC; c++) {
        float4 v = part[(long)c * stride + idx];
        s.x += v.x; s.y += v.y; s.z += v.z; s.w += v.w;
    }
    s.x = eluf(s.x); s.y = eluf(s.y); s.z = eluf(s.z); s.w = eluf(s.w);
    out[idx] = s;
}

extern "C" void kernel_launch(void* const* d_in, const int* in_sizes, int n_in,
                              void* d_out, int out_size, void* d_ws, size_t ws_size,
                              hipStream_t stream) {
    const float* h = (const float*)d_in[0];
    const float* W = (const float*)d_in[1];
    const float* a = (const float*)d_in[2];
    float* out = (float*)d_out;

    char* ws = (char*)d_ws;
    const size_t NB = (size_t)B * N;          // 16384 rows
    size_t off = 0;
    float* Wh    = (float*)(ws + off); off += NB * DF * sizeof(float);     // 4 MB
    float* f1    = (float*)(ws + off); off += NB * sizeof(float);
    float* f2    = (float*)(ws + off); off += NB * sizeof(float);
    float* denom = (float*)(ws + off); off += NB * sizeof(float);
    float4* col  = (float4*)(ws + off); off += NB * sizeof(float4);
    unsigned* f1maxU = (unsigned*)(ws + off); off += 64;
    off = (off + 255) & ~(size_t)255;
    float* part  = (float*)(ws + off);
    const size_t chunk_bytes = NB * DF * sizeof(float);                    // 4 MB

    int NC = 1;
    if (off + 8 * chunk_bytes <= ws_size) NC = 8;
    else if (off + 4 * chunk_bytes <= ws_size) NC = 4;
    else if (off + 2 * chunk_bytes <= ws_size) NC = 2;

    k_zero<<<(B * N + 255) / 256, 256, 0, stream>>>(denom, f1maxU);
    k_wh<<<NB / 16, 256, 0, stream>>>(h, W, Wh);
    k_f12<<<NB / 4, 256, 0, stream>>>(Wh, a, f1, f2, f1maxU);
    k_denom<<<dim3(N / 256, IC, B), 256, 0, stream>>>(f1, f2, f1maxU, denom);
    k_pack<<<NB / 256, 256, 0, stream>>>(f2, denom, f1maxU, col);

    if (NC == 8) {
        k_main<8, false><<<dim3(8, N / 256, B), 256, 0, stream>>>(Wh, f1, col, part);
        k_reduce<8><<<(NB * DF / 4) / 256, 256, 0, stream>>>((const float4*)part, (float4*)out);
    } else if (NC == 4) {
        k_main<4, false><<<dim3(4, N / 256, B), 256, 0, stream>>>(Wh, f1, col, part);
        k_reduce<4><<<(NB * DF / 4) / 256, 256, 0, stream>>>((const float4*)part, (float4*)out);
    } else if (NC == 2) {
        k_main<2, false><<<dim3(2, N / 256, B), 256, 0, stream>>>(Wh, f1, col, part);
        k_reduce<2><<<(NB * DF / 4) / 256, 256, 0, stream>>>((const float4*)part, (float4*)out);
    } else {
        k_main<1, true><<<dim3(1, N / 256, B), 256, 0, stream>>>(Wh, f1, col, out);
    }
}